// Round 3
// baseline (313.310 us; speedup 1.0000x reference)
//
#include <hip/hip_runtime.h>

// RandomTimeMask: out[n,c,l] = x[n,c,l] if ((l - starts[n,c]) mod L) >= L/4 else 0
// N=128, C=12, L=32768, mask_len=8192. Memory-bound elementwise streaming.
// Floor: write 201 MB + read ~151 MB (masked 25% skipped) ~= 352 MB @ ~6.3 TB/s
// mixed ~= 56 us. Harness resets (~244 us of fills) dominate dur_us.
//
// R3 changes vs R2:
//  - 4 float4 per thread (block covers 1024 f4 = 4096 floats; 8192 f4/row
//    % 1024 == 0 -> block still in ONE row, starts block-uniform). Halves
//    per-element index math and block count (12288 blocks).
//  - Keep non-temporal load/store (pure streaming, no reuse).
//  - Keep masked-run load skip (one contiguous circular 8192-run per row ->
//    branch wave-uniform except at the 2 run edges).

typedef float f4 __attribute__((ext_vector_type(4)));

__global__ __launch_bounds__(256) void RandomTimeMask_kernel(
    const f4* __restrict__ x,
    const int* __restrict__ starts,
    f4* __restrict__ out)
{
    const int LM   = 32767;  // L - 1
    const int MLEN = 8192;   // mask length

    int base4 = blockIdx.x * 1024 + threadIdx.x;  // first float4 index
    int row   = base4 >> 13;                      // / 8192 f4-per-row
    int s     = starts[row];                      // block-uniform
    int b0    = ((base4 & 8191) << 2) - s;        // elem offset minus start

#pragma unroll
    for (int j = 0; j < 4; ++j) {
        int idx4 = base4 + j * 256;
        int b    = b0 + j * 1024;

        bool k0 = ((b    ) & LM) >= MLEN;
        bool k1 = ((b + 1) & LM) >= MLEN;
        bool k2 = ((b + 2) & LM) >= MLEN;
        bool k3 = ((b + 3) & LM) >= MLEN;

        f4 v = {0.0f, 0.0f, 0.0f, 0.0f};
        if (k0 | k1 | k2 | k3) {                  // wave-uniform except at run edges
            v = __builtin_nontemporal_load(&x[idx4]);
            v[0] = k0 ? v[0] : 0.0f;
            v[1] = k1 ? v[1] : 0.0f;
            v[2] = k2 ? v[2] : 0.0f;
            v[3] = k3 ? v[3] : 0.0f;
        }
        __builtin_nontemporal_store(v, &out[idx4]);
    }
}

extern "C" void kernel_launch(void* const* d_in, const int* in_sizes, int n_in,
                              void* d_out, int out_size, void* d_ws, size_t ws_size,
                              hipStream_t stream) {
    const f4*  x      = (const f4*)d_in[0];
    const int* starts = (const int*)d_in[1];
    f4*        out    = (f4*)d_out;

    int total4 = out_size >> 2;      // 12,582,912 float4
    int block  = 256;
    int grid   = total4 / 1024;      // 12,288 blocks, 4 float4/thread

    RandomTimeMask_kernel<<<grid, block, 0, stream>>>(x, starts, out);
}

// Round 4
// 309.756 us; speedup vs baseline: 1.0115x; 1.0115x over previous
//
#include <hip/hip_runtime.h>

// RandomTimeMask: out[n,c,l] = x[n,c,l] if ((l - starts[n,c]) mod L) >= L/4 else 0
// N=128, C=12, L=32768, mask_len=8192. Memory-bound elementwise streaming.
//
// FINAL (revert to R2 config — best measured, 309.5 us):
//  - 2 float4/thread, 256-thread blocks (block covers 512 f4; 8192 f4/row
//    % 512 == 0 -> each block lies in ONE (n,c) row, starts block-uniform).
//  - Non-temporal load/store (pure streaming, zero reuse).
//  - Masked-run load skip: if all 4 elems masked, no global load. Mask is one
//    contiguous circular 8192-run per row -> branch wave-uniform except at
//    the 2 run edges. Saves ~25% of read traffic (~50 MB).
//
// Roofline: write 201 MB (irreducible: harness poisons out) + read ~151 MB
// ~= 352 MB @ ~6.5 TB/s mixed ~= 56 us. Kernel measures ~65 us (not in top-5
// dispatches; all top-5 are 122-us harness fills). dur_us is ~78% harness
// reset cost; R2->R3 4-f4 unroll was noise-negative -> this is the floor.

typedef float f4 __attribute__((ext_vector_type(4)));

__global__ __launch_bounds__(256) void RandomTimeMask_kernel(
    const f4* __restrict__ x,
    const int* __restrict__ starts,
    f4* __restrict__ out)
{
    const int LM   = 32767;  // L - 1
    const int MLEN = 8192;   // mask length

    int base4 = blockIdx.x * 512 + threadIdx.x;  // first float4 index
    int row   = base4 >> 13;                     // / 8192 f4-per-row
    int s     = starts[row];                     // block-uniform

#pragma unroll
    for (int j = 0; j < 2; ++j) {
        int idx4 = base4 + j * 256;
        int b    = ((idx4 & 8191) << 2) - s;     // elem offset minus start

        bool k0 = ((b    ) & LM) >= MLEN;
        bool k1 = ((b + 1) & LM) >= MLEN;
        bool k2 = ((b + 2) & LM) >= MLEN;
        bool k3 = ((b + 3) & LM) >= MLEN;

        f4 v = {0.0f, 0.0f, 0.0f, 0.0f};
        if (k0 | k1 | k2 | k3) {                 // wave-uniform except at run edges
            v = __builtin_nontemporal_load(&x[idx4]);
            v[0] = k0 ? v[0] : 0.0f;
            v[1] = k1 ? v[1] : 0.0f;
            v[2] = k2 ? v[2] : 0.0f;
            v[3] = k3 ? v[3] : 0.0f;
        }
        __builtin_nontemporal_store(v, &out[idx4]);
    }
}

extern "C" void kernel_launch(void* const* d_in, const int* in_sizes, int n_in,
                              void* d_out, int out_size, void* d_ws, size_t ws_size,
                              hipStream_t stream) {
    const f4*  x      = (const f4*)d_in[0];
    const int* starts = (const int*)d_in[1];
    f4*        out    = (f4*)d_out;

    int total4 = out_size >> 2;      // 12,582,912 float4
    int block  = 256;
    int grid   = total4 / 512;       // 24,576 blocks, 2 float4/thread

    RandomTimeMask_kernel<<<grid, block, 0, stream>>>(x, starts, out);
}